// Round 7
// baseline (205.314 us; speedup 1.0000x reference)
//
#include <hip/hip_runtime.h>
#include <math.h>

// Input [32, 3, 512, 512] f32 -> output [32, 27, 512, 512] f32.
// Round-0 body (best: 192 us) + G11 persistent grid (2048 blocks, 4 slices
// each) + m192-style bijective XCD swizzle so each XCD owns a contiguous
// 1/8 of the (batch, pixel) space (4 whole batches).
#define P4    65536          // fx4 groups per 512x512 plane
#define NCH   27
#define BATCH 32
#define NB    2048           // grid size; NB*256*4 == BATCH*P4 exactly

typedef float fx4 __attribute__((ext_vector_type(4)));

__global__ __launch_bounds__(256) void sclayer_58746562675072_kernel(
        const fx4* __restrict__ in, fx4* __restrict__ out) {
    // Bijective XCD swizzle: NB % 8 == 0.
    const int cpx = NB >> 3;                       // blocks per XCD group
    const int swz = (blockIdx.x & 7) * cpx + (blockIdx.x >> 3);
    const int span0 = swz * 1024;                  // block's first fx4 index

    constexpr int II[18] = {0,0,0, 1,1,1, 2,2,2, 3,3, 4,4, 5,5, 6, 7, 8};
    constexpr int JJ[18] = {0,3,6, 1,4,7, 2,5,8, 3,6, 4,7, 5,8, 6, 7, 8};

    #pragma unroll 1
    for (int it = 0; it < 4; ++it) {
        const int idx = span0 + it * 256 + threadIdx.x;  // [0, BATCH*P4)
        const int b = idx >> 16;                   // P4 == 2^16
        const int p = idx & (P4 - 1);

        const fx4* inb = in + (size_t)b * (3 * P4) + p;
        fx4 xv0 = inb[0 * P4];
        fx4 xv1 = inb[1 * P4];
        fx4 xv2 = inb[2 * P4];

        // base[c][k]: c = 0..2 raw, 3..5 cos, 6..8 sin; k = elem in fx4.
        float base[9][4];
        {
            const float xs[3][4] = {
                {xv0.x, xv0.y, xv0.z, xv0.w},
                {xv1.x, xv1.y, xv1.z, xv1.w},
                {xv2.x, xv2.y, xv2.z, xv2.w},
            };
            #pragma unroll
            for (int c = 0; c < 3; ++c) {
                #pragma unroll
                for (int k = 0; k < 4; ++k) {
                    float x = xs[c][k];
                    float s, co;
                    __sincosf(x, &s, &co);
                    base[c    ][k] = x;
                    base[c + 3][k] = co;
                    base[c + 6][k] = s;
                }
            }
        }

        fx4* outb = out + (size_t)b * (NCH * P4) + p;

        #pragma unroll
        for (int c = 0; c < 9; ++c) {
            fx4 v;
            v.x = base[c][0]; v.y = base[c][1]; v.z = base[c][2]; v.w = base[c][3];
            outb[c * P4] = v;
        }

        #pragma unroll
        for (int t = 0; t < 18; ++t) {
            fx4 v;
            v.x = base[II[t]][0] * base[JJ[t]][0];
            v.y = base[II[t]][1] * base[JJ[t]][1];
            v.z = base[II[t]][2] * base[JJ[t]][2];
            v.w = base[II[t]][3] * base[JJ[t]][3];
            outb[(9 + t) * P4] = v;
        }
    }
}

extern "C" void kernel_launch(void* const* d_in, const int* in_sizes, int n_in,
                              void* d_out, int out_size, void* d_ws, size_t ws_size,
                              hipStream_t stream) {
    const fx4* in  = (const fx4*)d_in[0];
    fx4*       out = (fx4*)d_out;
    sclayer_58746562675072_kernel<<<NB, 256, 0, stream>>>(in, out);
}

// Round 8
// 200.493 us; speedup vs baseline: 1.0240x; 1.0240x over previous
//
#include <hip/hip_runtime.h>
#include <math.h>

// FINAL: best variant (round-1 structure, 192 us ~ 5.2 TB/s combined).
// Input [32, 3, 512, 512] f32 -> output [32, 27, 512, 512] f32.
// One thread per 8 consecutive pixels (2 x fx4); read-once/write-once;
// 27 coalesced per-channel store streams through the normal L2 path.
// Measured ceiling evidence: NT stores 2.1x worse; channel-per-block
// (read-amplified) 1.75x worse; 2KB/16KB per-stream dwell, persistent
// grid + XCD swizzle all null (192-205 us band).
#define P4      65536        // float4 groups per plane
#define P8      32768        // 8-pixel groups per plane (2^15)
#define BATCH   32

typedef float fx4 __attribute__((ext_vector_type(4)));

__global__ __launch_bounds__(256) void sclayer_58746562675072_kernel(
        const fx4* __restrict__ in, fx4* __restrict__ out) {
    const int idx = blockIdx.x * blockDim.x + threadIdx.x;   // [0, BATCH*P8)
    const int b = idx >> 15;             // P8 == 2^15
    const int p = (idx & (P8 - 1)) * 2;  // fx4 index within plane (even)

    const fx4* inb = in + (size_t)b * (3 * P4) + p;
    fx4 xa[3], xb[3];
    #pragma unroll
    for (int c = 0; c < 3; ++c) {
        xa[c] = inb[c * P4];
        xb[c] = inb[c * P4 + 1];
    }

    // base[c][k]: c = 0..2 raw, 3..5 cos, 6..8 sin; k = pixel 0..7.
    float base[9][8];
    #pragma unroll
    for (int c = 0; c < 3; ++c) {
        const float xs[8] = {xa[c].x, xa[c].y, xa[c].z, xa[c].w,
                             xb[c].x, xb[c].y, xb[c].z, xb[c].w};
        #pragma unroll
        for (int k = 0; k < 8; ++k) {
            float x = xs[k];
            float s, co;
            __sincosf(x, &s, &co);
            base[c    ][k] = x;
            base[c + 3][k] = co;
            base[c + 6][k] = s;
        }
    }

    fx4* outb = out + (size_t)b * (27 * P4) + p;

    // Channels 0..8: base values.
    #pragma unroll
    for (int c = 0; c < 9; ++c) {
        fx4 v0, v1;
        v0.x = base[c][0]; v0.y = base[c][1]; v0.z = base[c][2]; v0.w = base[c][3];
        v1.x = base[c][4]; v1.y = base[c][5]; v1.z = base[c][6]; v1.w = base[c][7];
        outb[c * P4]     = v0;
        outb[c * P4 + 1] = v1;
    }

    // Channels 9..26: 18 pairwise products, torch-loop order
    // (i in 0..8, j in range(i, 9, 3)).
    constexpr int II[18] = {0,0,0, 1,1,1, 2,2,2, 3,3, 4,4, 5,5, 6, 7, 8};
    constexpr int JJ[18] = {0,3,6, 1,4,7, 2,5,8, 3,6, 4,7, 5,8, 6, 7, 8};
    #pragma unroll
    for (int t = 0; t < 18; ++t) {
        fx4 v0, v1;
        v0.x = base[II[t]][0] * base[JJ[t]][0];
        v0.y = base[II[t]][1] * base[JJ[t]][1];
        v0.z = base[II[t]][2] * base[JJ[t]][2];
        v0.w = base[II[t]][3] * base[JJ[t]][3];
        v1.x = base[II[t]][4] * base[JJ[t]][4];
        v1.y = base[II[t]][5] * base[JJ[t]][5];
        v1.z = base[II[t]][6] * base[JJ[t]][6];
        v1.w = base[II[t]][7] * base[JJ[t]][7];
        outb[(9 + t) * P4]     = v0;
        outb[(9 + t) * P4 + 1] = v1;
    }
}

extern "C" void kernel_launch(void* const* d_in, const int* in_sizes, int n_in,
                              void* d_out, int out_size, void* d_ws, size_t ws_size,
                              hipStream_t stream) {
    const fx4* in  = (const fx4*)d_in[0];
    fx4*       out = (fx4*)d_out;
    const int total_threads = BATCH * P8;        // 1,048,576
    const int block = 256;
    const int grid  = total_threads / block;     // 4096
    sclayer_58746562675072_kernel<<<grid, block, 0, stream>>>(in, out);
}